// Round 7
// baseline (10052.592 us; speedup 1.0000x reference)
//
#include <hip/hip_runtime.h>
#include <stdint.h>

typedef __bf16 bf16x8 __attribute__((ext_vector_type(8)));
typedef float f32x4 __attribute__((ext_vector_type(4)));

#define MFMA16(a,b,c) __builtin_amdgcn_mfma_f32_16x16x32_bf16((a),(b),(c),0,0,0)

__device__ __forceinline__ float bf2f(unsigned short u){
  union { float f; unsigned int i; } v; v.i = ((unsigned int)u)<<16; return v.f;
}
__device__ __forceinline__ unsigned short f2bf(float f){
  union { float f; unsigned int i; } v; v.f = f;
  unsigned int r = v.i + 0x7FFFu + ((v.i>>16)&1u);
  return (unsigned short)(r>>16);
}
__device__ __forceinline__ bf16x8 ldg8(const unsigned short* p){ return *(const bf16x8*)p; }
__device__ __forceinline__ float sigm(float x){ return 1.f/(1.f+__expf(-x)); }
__device__ __forceinline__ float tanhc(float x){
  x = fminf(fmaxf(x,-30.f),30.f);
  float e = __expf(2.f*x);
  return (e-1.f)/(e+1.f);
}

// ---------------- elementwise / layout kernels ----------------

__global__ void k_f2b(unsigned short* __restrict__ dst, const float* __restrict__ src, int n){
  int i = blockIdx.x*256 + threadIdx.x;
  if (i < n) dst[i] = f2bf(src[i]);
}

__global__ void k_zero(unsigned int* __restrict__ p, int nwords){
  int i = blockIdx.x*256 + threadIdx.x;
  if (i < nwords) p[i] = 0u;
}

__global__ void k_transpose(unsigned short* __restrict__ dst, const float* __restrict__ src,
                            int DR, int DC, int srcRowLen){
  __shared__ float tile[32][33];
  int r0 = blockIdx.x*32, c0 = blockIdx.y*32;
  int tx = threadIdx.x, ty = threadIdx.y; // 32 x 8
  #pragma unroll
  for (int i=0;i<4;i++){
    int c = c0 + ty + i*8, r = r0 + tx;
    float v = 0.f;
    if (c < DC && r < srcRowLen) v = src[(size_t)c*srcRowLen + r];
    tile[ty+i*8][tx] = v;
  }
  __syncthreads();
  #pragma unroll
  for (int i=0;i<4;i++){
    int r = r0 + ty + i*8, c = c0 + tx;
    if (r < DR && c < DC) dst[(size_t)r*DC + c] = f2bf(tile[tx][ty+i*8]);
  }
}

// half im2col: rows cover t = t0 .. t0+127 (8192 rows)
__global__ void k_im2col(unsigned short* __restrict__ Xcol, const float* __restrict__ x, int t0){
  long long idx = (long long)blockIdx.x*256 + threadIdx.x;
  if (idx >= (long long)8192*1792) return;
  int row = (int)(idx / 1792), c = (int)(idx % 1792);
  int t = t0 + (row >> 6), b = row & 63;
  float v = 0.f;
  if (c < 1771){
    int kt = c / 161, i = c % 161;
    int tt = t + kt - 5;
    if (tt >= 0 && tt < 256) v = x[((size_t)b*161 + i)*256 + tt];
  }
  Xcol[idx] = f2bf(v);
}

__global__ void k_x0p(unsigned short* __restrict__ x0p, const float* __restrict__ x){
  int idx = blockIdx.x*256 + threadIdx.x;
  if (idx >= 16384*192) return;
  int row = idx / 192, i = idx % 192;
  int t = row >> 6, b = row & 63;
  float v = 0.f;
  if (i < 161) v = x[((size_t)b*161 + i)*256 + t];
  x0p[idx] = f2bf(v);
}

__global__ void k_cmatT(unsigned short* __restrict__ dst, const float* __restrict__ convW){
  int idx = blockIdx.x*256 + threadIdx.x;
  if (idx >= 1792*4544) return;
  int crow = idx / 4544, col = idx % 4544;
  float v = 0.f;
  if (crow < 1771){
    int kt = crow / 161, i = crow % 161;
    int f = col / 71, ch = col % 71;
    int kf = i - 2*ch;
    if (kf >= 0 && kf < 21) v = convW[((size_t)f*21 + kf)*11 + kt];
  }
  dst[idx] = f2bf(v);
}

__global__ void k_cbexp(float* __restrict__ dst, const float* __restrict__ convb){
  int i = blockIdx.x*256 + threadIdx.x;
  if (i < 4544) dst[i] = convb[i/71];
}

__global__ void k_add4(float* __restrict__ dst, const float* a, const float* b,
                       const float* c, const float* d, int n){
  int i = blockIdx.x*256 + threadIdx.x;
  if (i >= n) return;
  float v = a ? a[i] : 0.f;
  if (b) v += b[i];
  if (c) v += c[i];
  if (d) v += d[i];
  dst[i] = v;
}

__global__ void k_matvec(float* __restrict__ out, const float* __restrict__ A, int lda, int K,
                         const float* __restrict__ v, const float* __restrict__ addv, int M){
  int row = blockIdx.x*4 + (threadIdx.x>>6);
  int lane = threadIdx.x & 63;
  if (row >= M) return;
  float s = 0.f;
  for (int k = lane; k < K; k += 64) s += A[(size_t)row*lda + k]*v[k];
  #pragma unroll
  for (int o=32;o;o>>=1) s += __shfl_down(s, o);
  if (lane == 0) out[row] = s + (addv ? addv[row] : 0.f);
}

// ---------------- GEMM kernels: C = A @ B^T  (A: MxK bf16, B: NxK bf16) ----------------

__global__ __launch_bounds__(256,1) void k_gemm_fast(
    unsigned short* __restrict__ C, const unsigned short* __restrict__ A,
    const unsigned short* __restrict__ B, const float* __restrict__ bias,
    int M, int N, int K, int lda, int ldb, int ldc)
{
  constexpr int LDT = 72;
  __shared__ unsigned short As[128*LDT];
  __shared__ unsigned short Bs[128*LDT];
  const int tid = threadIdx.x, wave = tid>>6, lane = tid&63;
  const int q = lane>>4, l15 = lane&15;
  const int m0 = blockIdx.x*128, n0 = blockIdx.y*128;
  const int mh = (wave>>1)*64, nh = (wave&1)*64;
  const int srow = tid>>3, scol = (tid&7)*8;
  f32x4 acc[4][4];
  #pragma unroll
  for (int i=0;i<4;i++)
    #pragma unroll
    for (int j=0;j<4;j++){ acc[i][j][0]=0.f; acc[i][j][1]=0.f; acc[i][j][2]=0.f; acc[i][j][3]=0.f; }

  for (int k0 = 0; k0 < K; k0 += 64){
    __syncthreads();
    #pragma unroll
    for (int p=0;p<4;p++){
      int r = p*32 + srow;
      *(bf16x8*)&As[r*LDT + scol] = ldg8(&A[(size_t)(m0+r)*lda + k0 + scol]);
      *(bf16x8*)&Bs[r*LDT + scol] = ldg8(&B[(size_t)(n0+r)*ldb + k0 + scol]);
    }
    __syncthreads();
    #pragma unroll
    for (int kc=0; kc<64; kc+=32){
      bf16x8 af[4], bf[4];
      #pragma unroll
      for (int i=0;i<4;i++) af[i] = *(const bf16x8*)&As[(mh + i*16 + l15)*LDT + kc + q*8];
      #pragma unroll
      for (int i=0;i<4;i++) bf[i] = *(const bf16x8*)&Bs[(nh + i*16 + l15)*LDT + kc + q*8];
      #pragma unroll
      for (int i=0;i<4;i++)
        #pragma unroll
        for (int j=0;j<4;j++)
          acc[i][j] = MFMA16(af[i], bf[j], acc[i][j]);
    }
  }
  #pragma unroll
  for (int i=0;i<4;i++){
    #pragma unroll
    for (int j=0;j<4;j++){
      int n = n0 + nh + j*16 + l15;
      float bz = bias ? bias[n] : 0.f;
      #pragma unroll
      for (int r=0;r<4;r++){
        int m = m0 + mh + i*16 + q*4 + r;
        C[(size_t)m*ldc + n] = f2bf(acc[i][j][r] + bz);
      }
    }
  }
}

__global__ __launch_bounds__(256,1) void k_gemm_small(
    unsigned short* __restrict__ C, const unsigned short* __restrict__ A,
    const unsigned short* __restrict__ B, const float* __restrict__ bias,
    const float* __restrict__ addT, int addT_ld,
    int M, int N, int K, int lda, int ldb, int ldc)
{
  constexpr int LDT = 40;
  __shared__ unsigned short As[64*LDT];
  __shared__ unsigned short Bs[64*LDT];
  const int tid = threadIdx.x, wave = tid>>6, lane = tid&63;
  const int q = lane>>4, l15 = lane&15;
  const int m0 = blockIdx.x*64, n0 = blockIdx.y*64;
  const int srow = tid>>2, scol = (tid&3)*8;
  f32x4 acc[4];
  #pragma unroll
  for (int j=0;j<4;j++){ acc[j][0]=0.f; acc[j][1]=0.f; acc[j][2]=0.f; acc[j][3]=0.f; }

  for (int k0=0;k0<K;k0+=32){
    __syncthreads();
    bf16x8 av;
    int gm = m0 + srow;
    if (gm < M) av = ldg8(&A[(size_t)gm*lda + k0 + scol]);
    else av = (bf16x8){(__bf16)0.f,(__bf16)0.f,(__bf16)0.f,(__bf16)0.f,(__bf16)0.f,(__bf16)0.f,(__bf16)0.f,(__bf16)0.f};
    bf16x8 bv = ldg8(&B[(size_t)(n0+srow)*ldb + k0 + scol]);
    *(bf16x8*)&As[srow*LDT + scol] = av;
    *(bf16x8*)&Bs[srow*LDT + scol] = bv;
    __syncthreads();
    bf16x8 af = *(const bf16x8*)&As[(wave*16 + l15)*LDT + q*8];
    #pragma unroll
    for (int j=0;j<4;j++){
      bf16x8 bf = *(const bf16x8*)&Bs[(j*16 + l15)*LDT + q*8];
      acc[j] = MFMA16(af, bf, acc[j]);
    }
  }
  #pragma unroll
  for (int j=0;j<4;j++){
    int n = n0 + j*16 + l15;
    float bz = bias ? bias[n] : 0.f;
    #pragma unroll
    for (int r=0;r<4;r++){
      int m = m0 + wave*16 + q*4 + r;
      if (m < M){
        float v = acc[j][r] + bz;
        if (addT) v += addT[(size_t)n*addT_ld + m];
        C[(size_t)m*ldc + n] = f2bf(v);
      }
    }
  }
}

// ---------------- stream-ordered superstep chain ----------------
// Launch s computes: h1(s) [bid<64], h2(s-1)/h3(s-1) [64..191], y(s-2) [192..202].
// Every read depends only on PREVIOUS launches -> stream ordering is the sync.
// No fences, no atomics, no polls, no LDS. Weights read global->register.

struct StepP {
  const unsigned short *W21, *W31, *Whh0, *Whh1, *Whh2, *Acat, *xg0, *x0p;
  const float *bc2, *bc3, *ybias;
  float *h1f, *h2f, *h3f;     // each 2 slots * 64*1024 f32
  unsigned short *hcat;       // 8 slots * 64*3072 bf16  [h1|h2|h3]
  float *out;                 // 256*64*161
};

__global__ void k_init(const float* __restrict__ h1in, const float* __restrict__ h2in,
                       const float* __restrict__ h3in,
                       float* __restrict__ h1f, float* __restrict__ h2f,
                       float* __restrict__ h3f, unsigned short* __restrict__ hcat){
  int i = blockIdx.x*256 + threadIdx.x;
  if (i >= 65536) return;
  int b = i>>10, j = i&1023;
  float v1 = h1in[i], v2 = h2in[i], v3 = h3in[i];
  h1f[65536+i]=v1; h2f[65536+i]=v2; h3f[65536+i]=v3;
  unsigned short* hc = hcat + 7*196608 + b*3072;
  hc[j]      = f2bf(v1);
  hc[1024+j] = f2bf(v2);
  hc[2048+j] = f2bf(v3);
}

__global__ __launch_bounds__(256,1) void k_step(StepP p, int s){
  const int bid = blockIdx.x, tid = threadIdx.x;
  const int wave = tid>>6, lane = tid&63;
  const int q = lane>>4, l15 = lane&15;

  if (bid < 64){
    // ======== h1(t), t = s ========
    if (s >= 256) return;
    const int t = s;
    const int j0 = bid*16;
    const unsigned short* ap = p.hcat + (size_t)((t+7)&7)*196608
                             + (size_t)(wave*16 + l15)*3072 + q*8;   // h1(t-1)
    const unsigned short* b0 = p.Whh0 + (size_t)(       j0 + l15)*1024 + q*8;
    const unsigned short* b1 = p.Whh0 + (size_t)(1024 + j0 + l15)*1024 + q*8;
    const unsigned short* b2 = p.Whh0 + (size_t)(2048 + j0 + l15)*1024 + q*8;
    f32x4 a0,a1,a2;
    a0[0]=a0[1]=a0[2]=a0[3]=0.f; a1=a0; a2=a0;
    #pragma unroll 4
    for (int kc=0;kc<1024;kc+=32){
      bf16x8 av = ldg8(ap + kc);
      a0 = MFMA16(av, ldg8(b0+kc), a0);
      a1 = MFMA16(av, ldg8(b1+kc), a1);
      a2 = MFMA16(av, ldg8(b2+kc), a2);
    }
    int jc = j0 + l15;
    const unsigned short* xg = p.xg0 + (size_t)t*196608;
    const float* hprev = p.h1f + ((t+1)&1)*65536;
    float* hnew = p.h1f + (t&1)*65536;
    unsigned short* hc = p.hcat + (size_t)(t&7)*196608;
    #pragma unroll
    for (int r=0;r<4;r++){
      int b = wave*16 + q*4 + r;
      float xr = bf2f(xg[b*3072 + jc]);
      float xz = bf2f(xg[b*3072 + 1024 + jc]);
      float xn = bf2f(xg[b*3072 + 2048 + jc]);
      float rg = sigm(xr + a0[r]);
      float zg = sigm(xz + a1[r]);
      float ng = tanhc(xn + rg*a2[r]);
      float hp = hprev[b*1024 + jc];
      float h = (1.f-zg)*ng + zg*hp;
      hnew[b*1024 + jc] = h;
      hc[b*3072 + jc] = f2bf(h);
    }
  } else if (bid < 192){
    // ======== h2(t)/h3(t), t = s-1 ========
    if (s < 1 || s > 256) return;
    const int t = s-1;
    bool is2 = (bid < 128);
    const int j0 = ((bid-64)&63)*16;
    const unsigned short* Wx = is2 ? p.W21 : p.W31;
    const unsigned short* Wh = is2 ? p.Whh1 : p.Whh2;
    const float* bc = is2 ? p.bc2 : p.bc3;
    float* hf = is2 ? p.h2f : p.h3f;
    const int coff = is2 ? 1024 : 2048;
    const unsigned short* a1p = p.hcat + (size_t)(t&7)*196608
                              + (size_t)(wave*16 + l15)*3072 + q*8;          // h1(t)
    const unsigned short* a2p = p.hcat + (size_t)((t+7)&7)*196608 + coff
                              + (size_t)(wave*16 + l15)*3072 + q*8;          // h{2,3}(t-1)
    const unsigned short* bx0 = Wx + (size_t)(       j0 + l15)*1216 + q*8;
    const unsigned short* bx1 = Wx + (size_t)(1024 + j0 + l15)*1216 + q*8;
    const unsigned short* bx2 = Wx + (size_t)(2048 + j0 + l15)*1216 + q*8;
    const unsigned short* bh0 = Wh + (size_t)(       j0 + l15)*1024 + q*8;
    const unsigned short* bh1 = Wh + (size_t)(1024 + j0 + l15)*1024 + q*8;
    const unsigned short* bh2 = Wh + (size_t)(2048 + j0 + l15)*1024 + q*8;
    f32x4 x0a,x1a,x2a,h0a,h1a,h2a;
    x0a[0]=x0a[1]=x0a[2]=x0a[3]=0.f; x1a=x0a; x2a=x0a; h0a=x0a; h1a=x0a; h2a=x0a;
    #pragma unroll 4
    for (int kc=0;kc<1024;kc+=32){
      bf16x8 av = ldg8(a1p + kc);
      x0a = MFMA16(av, ldg8(bx0+kc), x0a);
      x1a = MFMA16(av, ldg8(bx1+kc), x1a);
      x2a = MFMA16(av, ldg8(bx2+kc), x2a);
      bf16x8 ah = ldg8(a2p + kc);
      h0a = MFMA16(ah, ldg8(bh0+kc), h0a);
      h1a = MFMA16(ah, ldg8(bh1+kc), h1a);
      h2a = MFMA16(ah, ldg8(bh2+kc), h2a);
    }
    const unsigned short* xp = p.x0p + (size_t)(t*64 + wave*16 + l15)*192 + q*8;
    #pragma unroll
    for (int kc=0;kc<192;kc+=32){
      bf16x8 av = ldg8(xp + kc);
      x0a = MFMA16(av, ldg8(bx0+1024+kc), x0a);
      x1a = MFMA16(av, ldg8(bx1+1024+kc), x1a);
      x2a = MFMA16(av, ldg8(bx2+1024+kc), x2a);
    }
    int jc = j0 + l15;
    float bcr = bc[jc], bcz = bc[1024+jc], bcn = bc[2048+jc];
    const float* hprev = hf + ((t+1)&1)*65536;      // h(t-1)
    float* hnw = hf + (t&1)*65536;                  // h(t)
    unsigned short* hc = p.hcat + (size_t)(t&7)*196608 + coff;
    #pragma unroll
    for (int r=0;r<4;r++){
      int b = wave*16 + q*4 + r;
      float rg = sigm(x0a[r] + bcr + h0a[r]);
      float zg = sigm(x1a[r] + bcz + h1a[r]);
      float ng = tanhc(x2a[r] + bcn + rg*h2a[r]);
      float hp = hprev[b*1024 + jc];
      float h = (1.f-zg)*ng + zg*hp;
      hnw[b*1024 + jc] = h;
      hc[b*3072 + jc] = f2bf(h);
    }
  } else {
    // ======== y(t), t = s-2 ========
    if (s < 2) return;
    const int t = s-2;
    const int n0 = (bid-192)*16;
    const unsigned short* ap = p.hcat + (size_t)(t&7)*196608
                             + (size_t)(wave*16 + l15)*3072 + q*8;   // [h1|h2|h3](t)
    const unsigned short* bp = p.Acat + (size_t)(n0 + l15)*3072 + q*8;
    f32x4 acc; acc[0]=acc[1]=acc[2]=acc[3]=0.f;
    #pragma unroll 4
    for (int kc=0;kc<3072;kc+=32){
      acc = MFMA16(ldg8(ap+kc), ldg8(bp+kc), acc);
    }
    int o = n0 + l15;
    if (o < 161){
      float yb = p.ybias[o];
      #pragma unroll
      for (int r=0;r<4;r++){
        int b = wave*16 + q*4 + r;
        p.out[((size_t)t*64 + b)*161 + o] = acc[r] + yb;
      }
    }
  }
}

// ---------------- host launch ----------------

extern "C" void kernel_launch(void* const* d_in, const int* in_sizes, int n_in,
                              void* d_out, int out_size, void* d_ws, size_t ws_size,
                              hipStream_t stream)
{
  const float* x      = (const float*)d_in[0];
  const float* h1in   = (const float*)d_in[1];
  const float* h2in   = (const float*)d_in[2];
  const float* h3in   = (const float*)d_in[3];
  const float* convW  = (const float*)d_in[4];
  const float* convb  = (const float*)d_in[5];
  const float* Wih0   = (const float*)d_in[6];
  const float* Whh0   = (const float*)d_in[7];
  const float* Wih1   = (const float*)d_in[8];
  const float* Whh1   = (const float*)d_in[9];
  const float* Wih2   = (const float*)d_in[10];
  const float* Whh2   = (const float*)d_in[11];
  const float* in1W   = (const float*)d_in[12];
  const float* in1b   = (const float*)d_in[13];
  const float* in2W   = (const float*)d_in[14];
  const float* in2b   = (const float*)d_in[15];
  const float* ht0W   = (const float*)d_in[16];
  const float* ht0b   = (const float*)d_in[17];
  const float* ht1W   = (const float*)d_in[18];
  const float* ht1b   = (const float*)d_in[19];
  const float* ht2W   = (const float*)d_in[20];
  const float* ht2b   = (const float*)d_in[21];
  const float* ot0W   = (const float*)d_in[22];
  const float* ot0b   = (const float*)d_in[23];
  const float* ot1W   = (const float*)d_in[24];
  const float* ot1b   = (const float*)d_in[25];
  const float* ot2W   = (const float*)d_in[26];
  const float* ot2b   = (const float*)d_in[27];
  const float* outW   = (const float*)d_in[28];
  const float* outb   = (const float*)d_in[29];
  (void)in_sizes; (void)n_in;

  char* base = (char*)d_ws;
  size_t off = 0;
  auto alloc = [&](size_t bytes)->void* {
    void* p = base + off;
    off += (bytes + 255) & ~(size_t)255;
    return p;
  };

  // ---- persistent region (live across the scan) ----
  unsigned short* xg0   = (unsigned short*)alloc((size_t)16384*3072*2);  // 100.66 MB
  unsigned short* x0p   = (unsigned short*)alloc((size_t)16384*192*2);   // 6.29 MB
  unsigned short* W21   = (unsigned short*)alloc((size_t)3072*1216*2);   // 7.47 MB
  unsigned short* W31   = (unsigned short*)alloc((size_t)3072*1216*2);   // 7.47 MB
  unsigned short* Whh0b = (unsigned short*)alloc((size_t)3072*1024*2);
  unsigned short* Whh1b = (unsigned short*)alloc((size_t)3072*1024*2);
  unsigned short* Whh2b = (unsigned short*)alloc((size_t)3072*1024*2);
  unsigned short* Acat  = (unsigned short*)alloc((size_t)176*3072*2);
  unsigned short* hcat  = (unsigned short*)alloc((size_t)8*196608*2);    // 3.15 MB
  float* h1f   = (float*)alloc((size_t)2*65536*4);
  float* h2f   = (float*)alloc((size_t)2*65536*4);
  float* h3f   = (float*)alloc((size_t)2*65536*4);
  float* bc2   = (float*)alloc(3072*4);
  float* bc3   = (float*)alloc(3072*4);
  float* bg1   = (float*)alloc(3072*4);
  float* ybias = (float*)alloc(161*4);
  float* cbexp = (float*)alloc(4544*4);
  float* vb2   = (float*)alloc(1024*4);
  float* t1    = (float*)alloc(1024*4);
  float* vb3   = (float*)alloc(1024*4);
  float* vbo   = (float*)alloc(1024*4);

  // ---- temp arena, time-shared (44.20 MB = phase 1 peak) ----
  char* arena = (char*)alloc((size_t)3072*4544*2 + (size_t)1792*4544*2);
  unsigned short* Wih0b = (unsigned short*)arena;                              // phase 1
  unsigned short* CmatT = (unsigned short*)(arena + (size_t)3072*4544*2);
  unsigned short* Weff  = (unsigned short*)W21;                                // over W21+W31
  unsigned short* Xcol  = (unsigned short*)arena;                              // phase 2 (half: 8192x1792)
  char* a3 = arena;                                                            // phase 3
  auto alloc3 = [&](size_t bytes)->void*{ void* p=a3; a3 += (bytes+255)&~(size_t)255; return p; };
  unsigned short* Wih1b = (unsigned short*)alloc3((size_t)3072*1024*2);
  unsigned short* Wih2b = (unsigned short*)alloc3((size_t)3072*1024*2);
  unsigned short* ht0T  = (unsigned short*)alloc3((size_t)1024*1024*2);
  unsigned short* ht2bf = (unsigned short*)alloc3((size_t)1024*1024*2);
  unsigned short* VT    = (unsigned short*)alloc3((size_t)1024*1024*2);
  unsigned short* in1T  = (unsigned short*)alloc3((size_t)192*1024*2);
  unsigned short* in2T  = (unsigned short*)alloc3((size_t)192*1024*2);
  unsigned short* ot0T  = (unsigned short*)alloc3((size_t)1024*1024*2);
  unsigned short* ot1T  = (unsigned short*)alloc3((size_t)1024*1024*2);
  unsigned short* ot2T  = (unsigned short*)alloc3((size_t)1024*1024*2);
  unsigned short* outWb = (unsigned short*)alloc3((size_t)161*1024*2);

  if (off > ws_size){
    hipMemsetAsync(d_out, 0, (size_t)out_size*sizeof(float), stream);
    return;
  }

  auto g1 = [](int n){ return dim3((n+255)/256); };
  dim3 tb(32,8);

  // ---- Phase 1: Weff = Wih0 @ CmatT^T (conv folded into W_ih0) ----
  k_f2b<<<g1(3072*4544),256,0,stream>>>(Wih0b, Wih0, 3072*4544);
  k_cmatT<<<g1(1792*4544),256,0,stream>>>(CmatT, convW);
  k_gemm_fast<<<dim3(24,14),256,0,stream>>>(Weff, Wih0b, CmatT, nullptr,
                                            3072, 1792, 4544, 4544, 4544, 1792);

  // ---- Phase 2: xg0 = Xcol @ Weff^T + bg1, in two M-halves (t 0..127, 128..255) ----
  k_cbexp<<<g1(4544),256,0,stream>>>(cbexp, convb);
  k_matvec<<<dim3(768),256,0,stream>>>(bg1, Wih0, 4544, 4544, cbexp, nullptr, 3072);
  k_im2col<<<dim3(57344),256,0,stream>>>(Xcol, x, 0);
  k_gemm_fast<<<dim3(64,24),256,0,stream>>>(xg0, Xcol, Weff, bg1,
                                            8192, 3072, 1792, 1792, 1792, 3072);
  k_im2col<<<dim3(57344),256,0,stream>>>(Xcol, x, 128);
  k_gemm_fast<<<dim3(64,24),256,0,stream>>>(xg0 + (size_t)8192*3072, Xcol, Weff, bg1,
                                            8192, 3072, 1792, 1792, 1792, 3072);

  // ---- Phase 3: small combined weights ----
  k_f2b<<<g1(3072*1024),256,0,stream>>>(Wih1b, Wih1, 3072*1024);
  k_f2b<<<g1(3072*1024),256,0,stream>>>(Wih2b, Wih2, 3072*1024);
  k_f2b<<<g1(3072*1024),256,0,stream>>>(Whh0b, Whh0, 3072*1024);
  k_f2b<<<g1(3072*1024),256,0,stream>>>(Whh1b, Whh1, 3072*1024);
  k_f2b<<<g1(3072*1024),256,0,stream>>>(Whh2b, Whh2, 3072*1024);
  k_f2b<<<g1(1024*1024),256,0,stream>>>(ht2bf, ht2W, 1024*1024);
  k_f2b<<<g1(161*1024),256,0,stream>>>(outWb, outW, 161*1024);

  k_transpose<<<dim3(32,32),tb,0,stream>>>(ht0T, ht0W, 1024, 1024, 1024);
  k_transpose<<<dim3(6,32),tb,0,stream>>>(in1T, in1W, 192, 1024, 161);
  k_transpose<<<dim3(6,32),tb,0,stream>>>(in2T, in2W, 192, 1024, 161);
  k_transpose<<<dim3(32,32),tb,0,stream>>>(ot0T, ot0W, 1024, 1024, 1024);
  k_transpose<<<dim3(32,32),tb,0,stream>>>(ot1T, ot1W, 1024, 1024, 1024);
  k_transpose<<<dim3(32,32),tb,0,stream>>>(ot2T, ot2W, 1024, 1024, 1024);

  k_x0p<<<g1(16384*192),256,0,stream>>>(x0p, x);
  k_zero<<<g1(176*3072*2/4),256,0,stream>>>((unsigned int*)Acat, 176*3072*2/4);

  k_add4<<<g1(1024),256,0,stream>>>(vb2, in1b, ht0b, nullptr, nullptr, 1024);
  k_matvec<<<dim3(256),256,0,stream>>>(t1, ht2W, 1024, 1024, ht0b, nullptr, 1024);
  k_add4<<<g1(1024),256,0,stream>>>(vb3, in2b, ht1b, ht2b, t1, 1024);
  k_add4<<<g1(1024),256,0,stream>>>(vbo, ot0b, ot1b, ot2b, nullptr, 1024);
  k_matvec<<<dim3(768),256,0,stream>>>(bc2, Wih1, 1024, 1024, vb2, nullptr, 3072);
  k_matvec<<<dim3(768),256,0,stream>>>(bc3, Wih2, 1024, 1024, vb3, nullptr, 3072);
  k_matvec<<<dim3(41),256,0,stream>>>(ybias, outW, 1024, 1024, vbo, outb, 161);

  k_gemm_small<<<dim3(16,16),256,0,stream>>>(VT, ht0T, ht2bf, nullptr, ht1W, 1024,
                                             1024, 1024, 1024, 1024, 1024, 1024);
  k_gemm_small<<<dim3(48,16),256,0,stream>>>(W21, Wih1b, ht0T, nullptr, nullptr, 0,
                                             3072, 1024, 1024, 1024, 1024, 1216);
  k_gemm_small<<<dim3(48,3),256,0,stream>>>(W21+1024, Wih1b, in1T, nullptr, nullptr, 0,
                                             3072, 192, 1024, 1024, 1024, 1216);
  k_gemm_small<<<dim3(48,16),256,0,stream>>>(W31, Wih2b, VT, nullptr, nullptr, 0,
                                             3072, 1024, 1024, 1024, 1024, 1216);
  k_gemm_small<<<dim3(48,3),256,0,stream>>>(W31+1024, Wih2b, in2T, nullptr, nullptr, 0,
                                             3072, 192, 1024, 1024, 1024, 1216);
  k_gemm_small<<<dim3(3,16),256,0,stream>>>(Acat, outWb, ot0T, nullptr, nullptr, 0,
                                            161, 1024, 1024, 1024, 1024, 3072);
  k_gemm_small<<<dim3(3,16),256,0,stream>>>(Acat+1024, outWb, ot1T, nullptr, nullptr, 0,
                                            161, 1024, 1024, 1024, 1024, 3072);
  k_gemm_small<<<dim3(3,16),256,0,stream>>>(Acat+2048, outWb, ot2T, nullptr, nullptr, 0,
                                            161, 1024, 1024, 1024, 1024, 3072);

  // ---- h-state init + superstep chain (stream-ordered, no in-kernel sync) ----
  k_init<<<dim3(256),256,0,stream>>>(h1in, h2in, h3in, h1f, h2f, h3f, hcat);

  StepP sp;
  sp.W21 = W21; sp.W31 = W31; sp.Whh0 = Whh0b; sp.Whh1 = Whh1b; sp.Whh2 = Whh2b;
  sp.Acat = Acat; sp.xg0 = xg0; sp.x0p = x0p;
  sp.bc2 = bc2; sp.bc3 = bc3; sp.ybias = ybias;
  sp.h1f = h1f; sp.h2f = h2f; sp.h3f = h3f;
  sp.hcat = hcat; sp.out = (float*)d_out;
  for (int s = 0; s < 258; ++s){
    k_step<<<dim3(203),256,0,stream>>>(sp, s);
  }
}

// Round 9
// 8470.047 us; speedup vs baseline: 1.1868x; 1.1868x over previous
//
#include <hip/hip_runtime.h>
#include <hip/hip_cooperative_groups.h>
#include <stdint.h>

namespace cg = cooperative_groups;

typedef __bf16 bf16x8 __attribute__((ext_vector_type(8)));
typedef float f32x4 __attribute__((ext_vector_type(4)));

#define MFMA16(a,b,c) __builtin_amdgcn_mfma_f32_16x16x32_bf16((a),(b),(c),0,0,0)

__device__ __forceinline__ float bf2f(unsigned short u){
  union { float f; unsigned int i; } v; v.i = ((unsigned int)u)<<16; return v.f;
}
__device__ __forceinline__ unsigned short f2bf(float f){
  union { float f; unsigned int i; } v; v.f = f;
  unsigned int r = v.i + 0x7FFFu + ((v.i>>16)&1u);
  return (unsigned short)(r>>16);
}
__device__ __forceinline__ bf16x8 ldg8(const unsigned short* p){ return *(const bf16x8*)p; }
__device__ __forceinline__ bf16x8 lds8(const short* p){ return *(const bf16x8*)p; }
__device__ __forceinline__ float sigm(float x){ return 1.f/(1.f+__expf(-x)); }
__device__ __forceinline__ float tanhc(float x){
  x = fminf(fmaxf(x,-30.f),30.f);
  float e = __expf(2.f*x);
  return (e-1.f)/(e+1.f);
}

// Relaxed agent-scope atomic poll (proven r6). Caller issues __threadfence()
// after a satisfied poll (acquire) and before the publishing atomicAdd
// (release) — the ONLY cross-XCD protocol that has passed on this machine.
__device__ __forceinline__ void wait_ge(unsigned int* c, int need){
  if (need <= 0) return;
  int guard = 0;
  while ((int)__hip_atomic_load(c, __ATOMIC_RELAXED, __HIP_MEMORY_SCOPE_AGENT) < need){
    __builtin_amdgcn_s_sleep(8);
    if (++guard > 4000000) break;   // wrong-but-terminating safety valve
  }
}

// ---------------- elementwise / layout kernels ----------------

__global__ void k_f2b(unsigned short* __restrict__ dst, const float* __restrict__ src, int n){
  int i = blockIdx.x*256 + threadIdx.x;
  if (i < n) dst[i] = f2bf(src[i]);
}

__global__ void k_zero(unsigned int* __restrict__ p, int nwords){
  int i = blockIdx.x*256 + threadIdx.x;
  if (i < nwords) p[i] = 0u;
}

__global__ void k_transpose(unsigned short* __restrict__ dst, const float* __restrict__ src,
                            int DR, int DC, int srcRowLen){
  __shared__ float tile[32][33];
  int r0 = blockIdx.x*32, c0 = blockIdx.y*32;
  int tx = threadIdx.x, ty = threadIdx.y; // 32 x 8
  #pragma unroll
  for (int i=0;i<4;i++){
    int c = c0 + ty + i*8, r = r0 + tx;
    float v = 0.f;
    if (c < DC && r < srcRowLen) v = src[(size_t)c*srcRowLen + r];
    tile[ty+i*8][tx] = v;
  }
  __syncthreads();
  #pragma unroll
  for (int i=0;i<4;i++){
    int r = r0 + ty + i*8, c = c0 + tx;
    if (r < DR && c < DC) dst[(size_t)r*DC + c] = f2bf(tile[tx][ty+i*8]);
  }
}

// half im2col: rows cover t = t0 .. t0+127 (8192 rows)
__global__ void k_im2col(unsigned short* __restrict__ Xcol, const float* __restrict__ x, int t0){
  long long idx = (long long)blockIdx.x*256 + threadIdx.x;
  if (idx >= (long long)8192*1792) return;
  int row = (int)(idx / 1792), c = (int)(idx % 1792);
  int t = t0 + (row >> 6), b = row & 63;
  float v = 0.f;
  if (c < 1771){
    int kt = c / 161, i = c % 161;
    int tt = t + kt - 5;
    if (tt >= 0 && tt < 256) v = x[((size_t)b*161 + i)*256 + tt];
  }
  Xcol[idx] = f2bf(v);
}

__global__ void k_x0p(unsigned short* __restrict__ x0p, const float* __restrict__ x){
  int idx = blockIdx.x*256 + threadIdx.x;
  if (idx >= 16384*192) return;
  int row = idx / 192, i = idx % 192;
  int t = row >> 6, b = row & 63;
  float v = 0.f;
  if (i < 161) v = x[((size_t)b*161 + i)*256 + t];
  x0p[idx] = f2bf(v);
}

__global__ void k_cmatT(unsigned short* __restrict__ dst, const float* __restrict__ convW){
  int idx = blockIdx.x*256 + threadIdx.x;
  if (idx >= 1792*4544) return;
  int crow = idx / 4544, col = idx % 4544;
  float v = 0.f;
  if (crow < 1771){
    int kt = crow / 161, i = crow % 161;
    int f = col / 71, ch = col % 71;
    int kf = i - 2*ch;
    if (kf >= 0 && kf < 21) v = convW[((size_t)f*21 + kf)*11 + kt];
  }
  dst[idx] = f2bf(v);
}

__global__ void k_cbexp(float* __restrict__ dst, const float* __restrict__ convb){
  int i = blockIdx.x*256 + threadIdx.x;
  if (i < 4544) dst[i] = convb[i/71];
}

__global__ void k_add4(float* __restrict__ dst, const float* a, const float* b,
                       const float* c, const float* d, int n){
  int i = blockIdx.x*256 + threadIdx.x;
  if (i >= n) return;
  float v = a ? a[i] : 0.f;
  if (b) v += b[i];
  if (c) v += c[i];
  if (d) v += d[i];
  dst[i] = v;
}

__global__ void k_matvec(float* __restrict__ out, const float* __restrict__ A, int lda, int K,
                         const float* __restrict__ v, const float* __restrict__ addv, int M){
  int row = blockIdx.x*4 + (threadIdx.x>>6);
  int lane = threadIdx.x & 63;
  if (row >= M) return;
  float s = 0.f;
  for (int k = lane; k < K; k += 64) s += A[(size_t)row*lda + k]*v[k];
  #pragma unroll
  for (int o=32;o;o>>=1) s += __shfl_down(s, o);
  if (lane == 0) out[row] = s + (addv ? addv[row] : 0.f);
}

// ---------------- GEMM kernels: C = A @ B^T  (A: MxK bf16, B: NxK bf16) ----------------

__global__ __launch_bounds__(256,1) void k_gemm_fast(
    unsigned short* __restrict__ C, const unsigned short* __restrict__ A,
    const unsigned short* __restrict__ B, const float* __restrict__ bias,
    int M, int N, int K, int lda, int ldb, int ldc)
{
  constexpr int LDT = 72;
  __shared__ unsigned short As[128*LDT];
  __shared__ unsigned short Bs[128*LDT];
  const int tid = threadIdx.x, wave = tid>>6, lane = tid&63;
  const int q = lane>>4, l15 = lane&15;
  const int m0 = blockIdx.x*128, n0 = blockIdx.y*128;
  const int mh = (wave>>1)*64, nh = (wave&1)*64;
  const int srow = tid>>3, scol = (tid&7)*8;
  f32x4 acc[4][4];
  #pragma unroll
  for (int i=0;i<4;i++)
    #pragma unroll
    for (int j=0;j<4;j++){ acc[i][j][0]=0.f; acc[i][j][1]=0.f; acc[i][j][2]=0.f; acc[i][j][3]=0.f; }

  for (int k0 = 0; k0 < K; k0 += 64){
    __syncthreads();
    #pragma unroll
    for (int p=0;p<4;p++){
      int r = p*32 + srow;
      *(bf16x8*)&As[r*LDT + scol] = ldg8(&A[(size_t)(m0+r)*lda + k0 + scol]);
      *(bf16x8*)&Bs[r*LDT + scol] = ldg8(&B[(size_t)(n0+r)*ldb + k0 + scol]);
    }
    __syncthreads();
    #pragma unroll
    for (int kc=0; kc<64; kc+=32){
      bf16x8 af[4], bf[4];
      #pragma unroll
      for (int i=0;i<4;i++) af[i] = *(const bf16x8*)&As[(mh + i*16 + l15)*LDT + kc + q*8];
      #pragma unroll
      for (int i=0;i<4;i++) bf[i] = *(const bf16x8*)&Bs[(nh + i*16 + l15)*LDT + kc + q*8];
      #pragma unroll
      for (int i=0;i<4;i++)
        #pragma unroll
        for (int j=0;j<4;j++)
          acc[i][j] = MFMA16(af[i], bf[j], acc[i][j]);
    }
  }
  #pragma unroll
  for (int i=0;i<4;i++){
    #pragma unroll
    for (int j=0;j<4;j++){
      int n = n0 + nh + j*16 + l15;
      float bz = bias ? bias[n] : 0.f;
      #pragma unroll
      for (int r=0;r<4;r++){
        int m = m0 + mh + i*16 + q*4 + r;
        C[(size_t)m*ldc + n] = f2bf(acc[i][j][r] + bz);
      }
    }
  }
}

__global__ __launch_bounds__(256,1) void k_gemm_small(
    unsigned short* __restrict__ C, const unsigned short* __restrict__ A,
    const unsigned short* __restrict__ B, const float* __restrict__ bias,
    const float* __restrict__ addT, int addT_ld,
    int M, int N, int K, int lda, int ldb, int ldc)
{
  constexpr int LDT = 40;
  __shared__ unsigned short As[64*LDT];
  __shared__ unsigned short Bs[64*LDT];
  const int tid = threadIdx.x, wave = tid>>6, lane = tid&63;
  const int q = lane>>4, l15 = lane&15;
  const int m0 = blockIdx.x*64, n0 = blockIdx.y*64;
  const int srow = tid>>2, scol = (tid&3)*8;
  f32x4 acc[4];
  #pragma unroll
  for (int j=0;j<4;j++){ acc[j][0]=0.f; acc[j][1]=0.f; acc[j][2]=0.f; acc[j][3]=0.f; }

  for (int k0=0;k0<K;k0+=32){
    __syncthreads();
    bf16x8 av;
    int gm = m0 + srow;
    if (gm < M) av = ldg8(&A[(size_t)gm*lda + k0 + scol]);
    else av = (bf16x8){(__bf16)0.f,(__bf16)0.f,(__bf16)0.f,(__bf16)0.f,(__bf16)0.f,(__bf16)0.f,(__bf16)0.f,(__bf16)0.f};
    bf16x8 bv = ldg8(&B[(size_t)(n0+srow)*ldb + k0 + scol]);
    *(bf16x8*)&As[srow*LDT + scol] = av;
    *(bf16x8*)&Bs[srow*LDT + scol] = bv;
    __syncthreads();
    bf16x8 af = *(const bf16x8*)&As[(wave*16 + l15)*LDT + q*8];
    #pragma unroll
    for (int j=0;j<4;j++){
      bf16x8 bf = *(const bf16x8*)&Bs[(j*16 + l15)*LDT + q*8];
      acc[j] = MFMA16(af, bf, acc[j]);
    }
  }
  #pragma unroll
  for (int j=0;j<4;j++){
    int n = n0 + j*16 + l15;
    float bz = bias ? bias[n] : 0.f;
    #pragma unroll
    for (int r=0;r<4;r++){
      int m = m0 + wave*16 + q*4 + r;
      if (m < M){
        float v = acc[j][r] + bz;
        if (addT) v += addT[(size_t)n*addT_ld + m];
        C[(size_t)m*ldc + n] = f2bf(v);
      }
    }
  }
}

// ---------------- persistent dataflow scan kernel ----------------
// Roles: bid<64 G1 (16 cols), 64..149 G2 (12 cols), 150..235 G3 (12 cols),
// 236..246 Y (16 cols). Sync protocol = r6 (hardware-proven): poll relaxed ->
// __threadfence (acquire) -> syncthreads; ... syncthreads -> __threadfence
// (release) -> atomicAdd. NEW vs r6: ALL scan weights fit in LDS (12-col
// G2/G3 slices), eliminating the 4.4 MB/step of unique-per-block Whh-tail
// reads that streamed from HBM after each acquire-invalidate (r6 FETCH_SIZE
// 960 MB/dispatch = 22 us/step at measured 167 GB/s).

struct ScanP {
  const unsigned short *W21, *W31, *Whh0, *Whh1, *Whh2, *Acat, *xg0, *x0p;
  const float *bc2, *bc3, *ybias;
  const float *h1in, *h2in, *h3in;
  float *h1f, *h2f, *h3f;     // each 2 slots * 64*1024 f32
  unsigned short *hcat;       // 8 slots * 64*3072 bf16  [h1|h2|h3]
  unsigned int *cnt;          // c1 @0, c2 @32, c3 @64, cy @96
  float *out;                 // 256*64*161
};

#define SCAN_BLOCKS 247
#define SCAN_LDS 162432   // G2/G3: 36*1224 + 36*1032 shorts = 162,432 B

__global__ __launch_bounds__(256,1) void k_scan(ScanP p){
  extern __shared__ char smem[];
  short* lds = (short*)smem;
  const int bid = blockIdx.x, tid = threadIdx.x;
  const int wave = tid>>6, lane = tid&63;
  const int q = lane>>4, l15 = lane&15;
  unsigned int* c1 = p.cnt;
  unsigned int* c2 = p.cnt + 32;
  unsigned int* c3 = p.cnt + 64;
  unsigned int* cy = p.cnt + 96;

  // init h state: f32 slot 1, hcat slot 7 (plain stores; grid.sync publishes)
  for (int i = bid*256 + tid; i < 65536; i += SCAN_BLOCKS*256){
    int b = i>>10, j = i&1023;
    float v1 = p.h1in[i], v2 = p.h2in[i], v3 = p.h3in[i];
    p.h1f[65536+i]=v1; p.h2f[65536+i]=v2; p.h3f[65536+i]=v3;
    unsigned short* hc = p.hcat + 7*196608 + b*3072;
    hc[j]      = f2bf(v1);
    hc[1024+j] = f2bf(v2);
    hc[2048+j] = f2bf(v3);
  }

  // ---- LDS weight staging (one time) ----
  if (bid < 64){
    int j0 = bid*16;
    for (int it = tid; it < 6144; it += 256){           // 48 rows x 128 chunks of 8
      int row = it>>7, c8 = (it&127)*8;
      int grow = (row>>4)*1024 + j0 + (row&15);
      *(bf16x8*)&lds[row*1032 + c8] = ldg8(&p.Whh0[(size_t)grow*1024 + c8]);
    }
  } else if (bid < 236){
    bool is2 = (bid < 150);
    int jb = is2 ? (bid-64) : (bid-150);
    int j0 = jb*12;
    const unsigned short* Wx = is2 ? p.W21 : p.W31;
    const unsigned short* Wh = is2 ? p.Whh1 : p.Whh2;
    for (int it = tid; it < 5472; it += 256){           // 36 rows x 152 (K=1216)
      int row = it/152, c8 = (it%152)*8;
      int g = row/12, c = row - g*12;
      int jj = j0 + c; if (jj > 1023) jj = 1023;        // clamp within gate
      *(bf16x8*)&lds[row*1224 + c8] = ldg8(&Wx[(size_t)(g*1024 + jj)*1216 + c8]);
    }
    for (int it = tid; it < 4608; it += 256){           // 36 rows x 128 (K=1024)
      int row = it>>7, c8 = (it&127)*8;
      int g = row/12, c = row - g*12;
      int jj = j0 + c; if (jj > 1023) jj = 1023;
      *(bf16x8*)&lds[44064 + row*1032 + c8] = ldg8(&Wh[(size_t)(g*1024 + jj)*1024 + c8]);
    }
  } else {
    int n0 = (bid-236)*16;
    for (int it = tid; it < 6144; it += 256){           // 16 rows x 384
      int row = it/384, c8 = (it%384)*8;
      *(bf16x8*)&lds[row*3080 + c8] = ldg8(&p.Acat[(size_t)(n0+row)*3072 + c8]);
    }
  }

  cg::grid_group grid = cg::this_grid();
  grid.sync();   // once: init + staging visibility (proven mechanism)

  if (bid < 64){
    // ======== G1: h1(t), t=0..255 ========
    int j0 = bid*16;
    const short* b0 = lds + (0*16 + l15)*1032 + q*8;
    const short* b1 = lds + (1*16 + l15)*1032 + q*8;
    const short* b2 = lds + (2*16 + l15)*1032 + q*8;
    for (int t = 0; t < 256; ++t){
      if (tid == 0){
        wait_ge(c1, 64*t);
        wait_ge(c2, 86*(t-7));
        wait_ge(c3, 86*(t-7));
        wait_ge(cy, 11*(t-7));
        __threadfence();            // acquire
      }
      __syncthreads();
      const unsigned short* h1b = p.hcat + (size_t)((t+7)&7)*196608;
      const unsigned short* ap = h1b + (size_t)(wave*16 + l15)*3072 + q*8;
      f32x4 a0,a1,a2;
      a0[0]=a0[1]=a0[2]=a0[3]=0.f; a1=a0; a2=a0;
      #pragma unroll 8
      for (int kc=0;kc<1024;kc+=32){
        bf16x8 av = ldg8(ap + kc);
        a0 = MFMA16(av, lds8(b0+kc), a0);
        a1 = MFMA16(av, lds8(b1+kc), a1);
        a2 = MFMA16(av, lds8(b2+kc), a2);
      }
      int jc = j0 + l15;
      const unsigned short* xg = p.xg0 + (size_t)t*196608;
      const float* hprev = p.h1f + ((t+1)&1)*65536;
      float* hnew = p.h1f + (t&1)*65536;
      unsigned short* hc = p.hcat + (size_t)(t&7)*196608;
      #pragma unroll
      for (int r=0;r<4;r++){
        int b = wave*16 + q*4 + r;
        float xr = bf2f(xg[b*3072 + jc]);
        float xz = bf2f(xg[b*3072 + 1024 + jc]);
        float xn = bf2f(xg[b*3072 + 2048 + jc]);
        float rg = sigm(xr + a0[r]);
        float zg = sigm(xz + a1[r]);
        float ng = tanhc(xn + rg*a2[r]);
        float hp = hprev[b*1024 + jc];
        float h = (1.f-zg)*ng + zg*hp;
        hnew[b*1024 + jc] = h;
        hc[b*3072 + jc] = f2bf(h);
      }
      __syncthreads();              // drain all waves' stores
      if (tid == 0){
        __threadfence();            // release
        atomicAdd(c1, 1u);
      }
    }
  } else if (bid < 236){
    // ======== G2/G3: h2(t)/h3(t), 86 blocks each, 12 cols/block ========
    bool is2 = (bid < 150);
    int jb = is2 ? (bid-64) : (bid-150);
    int j0 = jb*12;
    const float* bc = is2 ? p.bc2 : p.bc3;
    float* hf = is2 ? p.h2f : p.h3f;
    unsigned int* cown = is2 ? c2 : c3;
    int coff = is2 ? 1024 : 2048;
    int bl = (l15 < 12) ? l15 : 0;    // duplicate B-row for masked lanes
    const short* bx0 = lds + (0*12 + bl)*1224 + q*8;
    const short* bx1 = lds + (1*12 + bl)*1224 + q*8;
    const short* bx2 = lds + (2*12 + bl)*1224 + q*8;
    const short* bh0 = lds + 44064 + (0*12 + bl)*1032 + q*8;
    const short* bh1 = lds + 44064 + (1*12 + bl)*1032 + q*8;
    const short* bh2 = lds + 44064 + (2*12 + bl)*1032 + q*8;
    int jc = j0 + l15;
    int jcc = (jc < 1024) ? jc : 1023;
    bool valid = (l15 < 12) && (jc < 1024);
    for (int t = 0; t < 256; ++t){
      if (tid == 0){
        wait_ge(c1, 64*(t+1));
        wait_ge(cown, 86*t);
        wait_ge(cy, 11*(t-7));
        __threadfence();
      }
      __syncthreads();
      const unsigned short* slotT  = p.hcat + (size_t)(t&7)*196608;          // h1(t)
      const unsigned short* slotT1 = p.hcat + (size_t)((t+7)&7)*196608;      // t-1
      const unsigned short* a1p = slotT + (size_t)(wave*16 + l15)*3072 + q*8;
      const unsigned short* a2p = slotT1 + coff + (size_t)(wave*16 + l15)*3072 + q*8;
      f32x4 x0a,x1a,x2a,h0a,h1a,h2a;
      x0a[0]=x0a[1]=x0a[2]=x0a[3]=0.f; x1a=x0a; x2a=x0a; h0a=x0a; h1a=x0a; h2a=x0a;
      #pragma unroll 4
      for (int kc=0;kc<1024;kc+=32){
        bf16x8 av = ldg8(a1p + kc);
        x0a = MFMA16(av, lds8(bx0+kc), x0a);
        x1a = MFMA16(av, lds8(bx1+kc), x1a);
        x2a = MFMA16(av, lds8(bx2+kc), x2a);
        bf16x8 ah = ldg8(a2p + kc);
        h0a = MFMA16(ah, lds8(bh0+kc), h0a);
        h1a = MFMA16(ah, lds8(bh1+kc), h1a);
        h2a = MFMA16(ah, lds8(bh2+kc), h2a);
      }
      const unsigned short* xp = p.x0p + (size_t)(t*64 + wave*16 + l15)*192 + q*8;
      #pragma unroll
      for (int kc=0;kc<192;kc+=32){
        bf16x8 av = ldg8(xp + kc);
        x0a = MFMA16(av, lds8(bx0+1024+kc), x0a);
        x1a = MFMA16(av, lds8(bx1+1024+kc), x1a);
        x2a = MFMA16(av, lds8(bx2+1024+kc), x2a);
      }
      float bcr = bc[jcc], bcz = bc[1024+jcc], bcn = bc[2048+jcc];
      const float* hprev = hf + ((t+1)&1)*65536;      // h(t-1)
      float* hnw = hf + (t&1)*65536;                  // h(t)
      unsigned short* hc = p.hcat + (size_t)(t&7)*196608 + coff;
      #pragma unroll
      for (int r=0;r<4;r++){
        int b = wave*16 + q*4 + r;
        float rg = sigm(x0a[r] + bcr + h0a[r]);
        float zg = sigm(x1a[r] + bcz + h1a[r]);
        float ng = tanhc(x2a[r] + bcn + rg*h2a[r]);
        float hp = hprev[b*1024 + jcc];
        float h = (1.f-zg)*ng + zg*hp;
        if (valid){
          hnw[b*1024 + jc] = h;
          hc[b*3072 + jc] = f2bf(h);
        }
      }
      __syncthreads();
      if (tid == 0){
        __threadfence();
        atomicAdd(cown, 1u);
      }
    }
  } else {
    // ======== Y: y(t), t=0..255 ========
    int n0 = (bid-236)*16;
    const short* bp = lds + l15*3080 + q*8;
    for (int t = 0; t < 256; ++t){
      if (tid == 0){
        wait_ge(c1, 64*(t+1));
        wait_ge(c2, 86*(t+1));
        wait_ge(c3, 86*(t+1));
        __threadfence();
      }
      __syncthreads();
      const unsigned short* hb = p.hcat + (size_t)(t&7)*196608;
      const unsigned short* ap = hb + (size_t)(wave*16 + l15)*3072 + q*8;
      f32x4 acc; acc[0]=acc[1]=acc[2]=acc[3]=0.f;
      #pragma unroll 8
      for (int kc=0;kc<3072;kc+=32){
        acc = MFMA16(ldg8(ap+kc), lds8(bp+kc), acc);
      }
      int o = n0 + l15;
      if (o < 161){
        float yb = p.ybias[o];
        #pragma unroll
        for (int r=0;r<4;r++){
          int b = wave*16 + q*4 + r;
          p.out[((size_t)t*64 + b)*161 + o] = acc[r] + yb;
        }
      }
      __syncthreads();
      if (tid == 0){
        __threadfence();
        atomicAdd(cy, 1u);
      }
    }
  }
}

// ---------------- host launch ----------------

extern "C" void kernel_launch(void* const* d_in, const int* in_sizes, int n_in,
                              void* d_out, int out_size, void* d_ws, size_t ws_size,
                              hipStream_t stream)
{
  const float* x      = (const float*)d_in[0];
  const float* h1in   = (const float*)d_in[1];
  const float* h2in   = (const float*)d_in[2];
  const float* h3in   = (const float*)d_in[3];
  const float* convW  = (const float*)d_in[4];
  const float* convb  = (const float*)d_in[5];
  const float* Wih0   = (const float*)d_in[6];
  const float* Whh0   = (const float*)d_in[7];
  const float* Wih1   = (const float*)d_in[8];
  const float* Whh1   = (const float*)d_in[9];
  const float* Wih2   = (const float*)d_in[10];
  const float* Whh2   = (const float*)d_in[11];
  const float* in1W   = (const float*)d_in[12];
  const float* in1b   = (const float*)d_in[13];
  const float* in2W   = (const float*)d_in[14];
  const float* in2b   = (const float*)d_in[15];
  const float* ht0W   = (const float*)d_in[16];
  const float* ht0b   = (const float*)d_in[17];
  const float* ht1W   = (const float*)d_in[18];
  const float* ht1b   = (const float*)d_in[19];
  const float* ht2W   = (const float*)d_in[20];
  const float* ht2b   = (const float*)d_in[21];
  const float* ot0W   = (const float*)d_in[22];
  const float* ot0b   = (const float*)d_in[23];
  const float* ot1W   = (const float*)d_in[24];
  const float* ot1b   = (const float*)d_in[25];
  const float* ot2W   = (const float*)d_in[26];
  const float* ot2b   = (const float*)d_in[27];
  const float* outW   = (const float*)d_in[28];
  const float* outb   = (const float*)d_in[29];
  (void)in_sizes; (void)n_in;

  char* base = (char*)d_ws;
  size_t off = 0;
  auto alloc = [&](size_t bytes)->void* {
    void* p = base + off;
    off += (bytes + 255) & ~(size_t)255;
    return p;
  };

  // ---- persistent region (live across the scan) ----
  unsigned short* xg0   = (unsigned short*)alloc((size_t)16384*3072*2);  // 100.66 MB
  unsigned short* x0p   = (unsigned short*)alloc((size_t)16384*192*2);   // 6.29 MB
  unsigned short* W21   = (unsigned short*)alloc((size_t)3072*1216*2);   // 7.47 MB
  unsigned short* W31   = (unsigned short*)alloc((size_t)3072*1216*2);   // 7.47 MB
  unsigned short* Whh0b = (unsigned short*)alloc((size_t)3072*1024*2);
  unsigned short* Whh1b = (unsigned short*)alloc((size_t)3072*1024*2);
  unsigned short* Whh2b = (unsigned short*)alloc((size_t)3072*1024*2);
  unsigned short* Acat  = (unsigned short*)alloc((size_t)176*3072*2);
  unsigned short* hcat  = (unsigned short*)alloc((size_t)8*196608*2);    // 3.15 MB
  float* h1f   = (float*)alloc((size_t)2*65536*4);
  float* h2f   = (float*)alloc((size_t)2*65536*4);
  float* h3f   = (float*)alloc((size_t)2*65536*4);
  unsigned int* cnt = (unsigned int*)alloc(512);
  float* bc2   = (float*)alloc(3072*4);
  float* bc3   = (float*)alloc(3072*4);
  float* bg1   = (float*)alloc(3072*4);
  float* ybias = (float*)alloc(161*4);
  float* cbexp = (float*)alloc(4544*4);
  float* vb2   = (float*)alloc(1024*4);
  float* t1    = (float*)alloc(1024*4);
  float* vb3   = (float*)alloc(1024*4);
  float* vbo   = (float*)alloc(1024*4);

  // ---- temp arena, time-shared (44.20 MB = phase 1 peak) ----
  char* arena = (char*)alloc((size_t)3072*4544*2 + (size_t)1792*4544*2);
  unsigned short* Wih0b = (unsigned short*)arena;                              // phase 1
  unsigned short* CmatT = (unsigned short*)(arena + (size_t)3072*4544*2);
  unsigned short* Weff  = (unsigned short*)W21;                                // over W21+W31
  unsigned short* Xcol  = (unsigned short*)arena;                              // phase 2 (half: 8192x1792)
  char* a3 = arena;                                                            // phase 3
  auto alloc3 = [&](size_t bytes)->void*{ void* p=a3; a3 += (bytes+255)&~(size_t)255; return p; };
  unsigned short* Wih1b = (unsigned short*)alloc3((size_t)3072*1024*2);
  unsigned short* Wih2b = (unsigned short*)alloc3((size_t)3072*1024*2);
  unsigned short* ht0T  = (unsigned short*)alloc3((size_t)1024*1024*2);
  unsigned short* ht2bf = (unsigned short*)alloc3((size_t)1024*1024*2);
  unsigned short* VT    = (unsigned short*)alloc3((size_t)1024*1024*2);
  unsigned short* in1T  = (unsigned short*)alloc3((size_t)192*1024*2);
  unsigned short* in2T  = (unsigned short*)alloc3((size_t)192*1024*2);
  unsigned short* ot0T  = (unsigned short*)alloc3((size_t)1024*1024*2);
  unsigned short* ot1T  = (unsigned short*)alloc3((size_t)1024*1024*2);
  unsigned short* ot2T  = (unsigned short*)alloc3((size_t)1024*1024*2);
  unsigned short* outWb = (unsigned short*)alloc3((size_t)161*1024*2);

  if (off > ws_size){
    hipMemsetAsync(d_out, 0, (size_t)out_size*sizeof(float), stream);
    return;
  }

  auto g1 = [](int n){ return dim3((n+255)/256); };
  dim3 tb(32,8);

  // ---- Phase 1: Weff = Wih0 @ CmatT^T (conv folded into W_ih0) ----
  k_f2b<<<g1(3072*4544),256,0,stream>>>(Wih0b, Wih0, 3072*4544);
  k_cmatT<<<g1(1792*4544),256,0,stream>>>(CmatT, convW);
  k_gemm_fast<<<dim3(24,14),256,0,stream>>>(Weff, Wih0b, CmatT, nullptr,
                                            3072, 1792, 4544, 4544, 4544, 1792);

  // ---- Phase 2: xg0 = Xcol @ Weff^T + bg1, in two M-halves ----
  k_cbexp<<<g1(4544),256,0,stream>>>(cbexp, convb);
  k_matvec<<<dim3(768),256,0,stream>>>(bg1, Wih0, 4544, 4544, cbexp, nullptr, 3072);
  k_im2col<<<dim3(57344),256,0,stream>>>(Xcol, x, 0);
  k_gemm_fast<<<dim3(64,24),256,0,stream>>>(xg0, Xcol, Weff, bg1,
                                            8192, 3072, 1792, 1792, 1792, 3072);
  k_im2col<<<dim3(57344),256,0,stream>>>(Xcol, x, 128);
  k_gemm_fast<<<dim3(64,24),256,0,stream>>>(xg0 + (size_t)8192*3072, Xcol, Weff, bg1,
                                            8192, 3072, 1792, 1792, 1792, 3072);

  // ---- Phase 3: small combined weights ----
  k_f2b<<<g1(3072*1024),256,0,stream>>>(Wih1b, Wih1, 3072*1024);
  k_f2b<<<g1(3072*1024),256,0,stream>>>(Wih2b, Wih2, 3072*1024);
  k_f2b<<<g1(3072*1024),256,0,stream>>>(Whh0b, Whh0, 3072*1024);
  k_f2b<<<g1(3072*1024),256,0,stream>>>(Whh1b, Whh1, 3072*1024);
  k_f2b<<<g1(3072*1024),256,0,stream>>>(Whh2b, Whh2, 3072*1024);
  k_f2b<<<g1(1024*1024),256,0,stream>>>(ht2bf, ht2W, 1024*1024);
  k_f2b<<<g1(161*1024),256,0,stream>>>(outWb, outW, 161*1024);

  k_transpose<<<dim3(32,32),tb,0,stream>>>(ht0T, ht0W, 1024, 1024, 1024);
  k_transpose<<<dim3(6,32),tb,0,stream>>>(in1T, in1W, 192, 1024, 161);
  k_transpose<<<dim3(6,32),tb,0,stream>>>(in2T, in2W, 192, 1024, 161);
  k_transpose<<<dim3(32,32),tb,0,stream>>>(ot0T, ot0W, 1024, 1024, 1024);
  k_transpose<<<dim3(32,32),tb,0,stream>>>(ot1T, ot1W, 1024, 1024, 1024);
  k_transpose<<<dim3(32,32),tb,0,stream>>>(ot2T, ot2W, 1024, 1024, 1024);

  k_x0p<<<g1(16384*192),256,0,stream>>>(x0p, x);
  k_zero<<<g1(176*3072*2/4),256,0,stream>>>((unsigned int*)Acat, 176*3072*2/4);
  k_zero<<<dim3(1),256,0,stream>>>(cnt, 128);

  k_add4<<<g1(1024),256,0,stream>>>(vb2, in1b, ht0b, nullptr, nullptr, 1024);
  k_matvec<<<dim3(256),256,0,stream>>>(t1, ht2W, 1024, 1024, ht0b, nullptr, 1024);
  k_add4<<<g1(1024),256,0,stream>>>(vb3, in2b, ht1b, ht2b, t1, 1024);
  k_add4<<<g1(1024),256,0,stream>>>(vbo, ot0b, ot1b, ot2b, nullptr, 1024);
  k_matvec<<<dim3(768),256,0,stream>>>(bc2, Wih1, 1024, 1024, vb2, nullptr, 3072);
  k_matvec<<<dim3(768),256,0,stream>>>(bc3, Wih2, 1024, 1024, vb3, nullptr, 3072);
  k_matvec<<<dim3(41),256,0,stream>>>(ybias, outW, 1024, 1024, vbo, outb, 161);

  k_gemm_small<<<dim3(16,16),256,0,stream>>>(VT, ht0T, ht2bf, nullptr, ht1W, 1024,
                                             1024, 1024, 1024, 1024, 1024, 1024);
  k_gemm_small<<<dim3(48,16),256,0,stream>>>(W21, Wih1b, ht0T, nullptr, nullptr, 0,
                                             3072, 1024, 1024, 1024, 1024, 1216);
  k_gemm_small<<<dim3(48,3),256,0,stream>>>(W21+1024, Wih1b, in1T, nullptr, nullptr, 0,
                                             3072, 192, 1024, 1024, 1024, 1216);
  k_gemm_small<<<dim3(48,16),256,0,stream>>>(W31, Wih2b, VT, nullptr, nullptr, 0,
                                             3072, 1024, 1024, 1024, 1024, 1216);
  k_gemm_small<<<dim3(48,3),256,0,stream>>>(W31+1024, Wih2b, in2T, nullptr, nullptr, 0,
                                             3072, 192, 1024, 1024, 1024, 1216);
  k_gemm_small<<<dim3(3,16),256,0,stream>>>(Acat, outWb, ot0T, nullptr, nullptr, 0,
                                            161, 1024, 1024, 1024, 1024, 3072);
  k_gemm_small<<<dim3(3,16),256,0,stream>>>(Acat+1024, outWb, ot1T, nullptr, nullptr, 0,
                                            161, 1024, 1024, 1024, 1024, 3072);
  k_gemm_small<<<dim3(3,16),256,0,stream>>>(Acat+2048, outWb, ot2T, nullptr, nullptr, 0,
                                            161, 1024, 1024, 1024, 1024, 3072);

  // ---- persistent dataflow scan ----
  hipFuncSetAttribute((const void*)k_scan, hipFuncAttributeMaxDynamicSharedMemorySize, SCAN_LDS);
  ScanP sp;
  sp.W21 = W21; sp.W31 = W31; sp.Whh0 = Whh0b; sp.Whh1 = Whh1b; sp.Whh2 = Whh2b;
  sp.Acat = Acat; sp.xg0 = xg0; sp.x0p = x0p;
  sp.bc2 = bc2; sp.bc3 = bc3; sp.ybias = ybias;
  sp.h1in = h1in; sp.h2in = h2in; sp.h3in = h3in;
  sp.h1f = h1f; sp.h2f = h2f; sp.h3f = h3f;
  sp.hcat = hcat; sp.cnt = cnt; sp.out = (float*)d_out;
  void* args[] = { &sp };
  hipLaunchCooperativeKernel((const void*)k_scan, dim3(SCAN_BLOCKS), dim3(256),
                             args, SCAN_LDS, stream);
}